// Round 1
// baseline (11.882 us; speedup 1.0000x reference)
//
#include <hip/hip_runtime.h>
#include <math.h>

// Circuit topology is compile-time constant (registered buffers in the ref):
//   data[0]=lp[:,0]  data[1]=lp[:,1]  data[2]=lp[:,2]
//   data[3]=lp[:,1]  data[4]=lp[:,2]  data[6]=lp[:,0]
//   data[9]=-1000, data[5]=data[7]=data[8]=0 initially
//   node5 = mean_i lse(d1[i]+d2[i], d3[i]+d4[i])   (scalar broadcast)
//   node7 = mean_i lse(d1[i]+d4[i], d9[i]+d9[i])
//   out[i] = lse(d0[i]+node5, d6[i]+node7)
// Total ~50 FLOPs -> single-thread kernel; runtime = launch latency.

__device__ __forceinline__ float lse2(float a, float b) {
    float m = fmaxf(a, b);
    return m + logf(expf(a - m) + expf(b - m));
}

__global__ void MyModel_61933428411467_kernel(const float* __restrict__ lp,
                                              float* __restrict__ out) {
    if (threadIdx.x != 0 || blockIdx.x != 0) return;

    float d0[5], d1[5], d2[5];
    #pragma unroll
    for (int i = 0; i < 5; ++i) {
        d0[i] = lp[i * 3 + 0];
        d1[i] = lp[i * 3 + 1];
        d2[i] = lp[i * 3 + 2];
    }
    const float NEG_BIG = -1000.0f;

    // Level 0, node 5: branches (d1+d2) and (d3+d4) == (d1+d2); mean over i.
    float s5 = 0.0f;
    #pragma unroll
    for (int i = 0; i < 5; ++i) {
        float b0 = d1[i] + d2[i];   // data[1]+data[2]
        float b1 = d1[i] + d2[i];   // data[3]+data[4] (same gathers)
        s5 += lse2(b0, b1);
    }
    s5 *= 0.2f;

    // Level 0, node 7: branches (d1+d4) and (d9+d9) = -2000; mean over i.
    float s7 = 0.0f;
    #pragma unroll
    for (int i = 0; i < 5; ++i) {
        float b0 = d1[i] + d2[i];            // data[1]+data[4] = lp1+lp2
        float b1 = NEG_BIG + NEG_BIG;        // data[9]+data[9]
        s7 += lse2(b0, b1);
    }
    s7 *= 0.2f;

    // Root node 8: out[i] = lse(d0[i]+node5, d6[i]+node7); d6 == d0 == lp[:,0]
    #pragma unroll
    for (int i = 0; i < 5; ++i) {
        out[i] = lse2(d0[i] + s5, d0[i] + s7);
    }
}

extern "C" void kernel_launch(void* const* d_in, const int* in_sizes, int n_in,
                              void* d_out, int out_size, void* d_ws, size_t ws_size,
                              hipStream_t stream) {
    const float* lp = (const float*)d_in[0];
    float* out = (float*)d_out;
    MyModel_61933428411467_kernel<<<1, 64, 0, stream>>>(lp, out);
}